// Round 1
// baseline (4966.108 us; speedup 1.0000x reference)
//
#include <hip/hip_runtime.h>

#define NBINS 256
constexpr int W_IMG = 512;
constexpr int H_IMG = 512;
constexpr int IMG_ELEMS = H_IMG * W_IMG;          // 262144
constexpr int PAIRS = (H_IMG - 1) * W_IMG;        // 261632
constexpr int PAIRS4 = PAIRS / 4;                 // 65408 (divisible: 261632/4)
constexpr int NIMG = 96;
constexpr int HIST = NBINS * NBINS;               // 65536

// cos(pi*d) for d in [0,1): v_cos_f32 takes revolutions -> cos(2*pi*x), so x = d/2.
__device__ __forceinline__ float cospi_fast(float d) {
    return __builtin_amdgcn_cosf(0.5f * d);
}

__global__ void zero_kernel(float* __restrict__ out) {
    int i = blockIdx.x * blockDim.x + threadIdx.x;
    float4 z = make_float4(0.f, 0.f, 0.f, 0.f);
    reinterpret_cast<float4*>(out)[i] = z;
}

__global__ void hist_kernel(const float* __restrict__ X, float* __restrict__ out) {
    const int bc = blockIdx.y;
    const float* img = X + (size_t)bc * IMG_ELEMS;
    float* __restrict__ h = out + (size_t)bc * HIST;
    const int stride = blockDim.x * gridDim.x;
    for (int k4 = blockIdx.x * blockDim.x + threadIdx.x; k4 < PAIRS4; k4 += stride) {
        float4 av = reinterpret_cast<const float4*>(img)[k4];
        float4 bv = reinterpret_cast<const float4*>(img + W_IMG)[k4];
        const float* ap = &av.x;
        const float* bp = &bv.x;
#pragma unroll
        for (int j = 0; j < 4; ++j) {
            float a = ap[j];
            float b = bp[j];
            float fa = floorf(a); fa = fminf(fa, 255.0f);
            float fb = floorf(b); fb = fminf(fb, 255.0f);
            float da = a - fa, db = b - fb;
            float wa0 = 0.5f + 0.5f * cospi_fast(da);
            float wb0 = 0.5f + 0.5f * cospi_fast(db);
            float wa1 = 1.0f - wa0, wb1 = 1.0f - wb0;
            int ia0 = (int)fa, ib0 = (int)fb;
            int ia1 = min(ia0 + 1, NBINS - 1);
            int ib1 = min(ib0 + 1, NBINS - 1);
            unsafeAtomicAdd(&h[ia0 * NBINS + ib0], wa0 * wb0);
            unsafeAtomicAdd(&h[ia0 * NBINS + ib1], wa0 * wb1);
            unsafeAtomicAdd(&h[ia1 * NBINS + ib0], wa1 * wb0);
            unsafeAtomicAdd(&h[ia1 * NBINS + ib1], wa1 * wb1);
        }
    }
}

__global__ void max_kernel(const float* __restrict__ out, float* __restrict__ vmax) {
    const int bc = blockIdx.x;
    const float* h = out + (size_t)bc * HIST;
    float m = 0.0f;
    for (int i = threadIdx.x; i < HIST; i += blockDim.x) m = fmaxf(m, h[i]);
#pragma unroll
    for (int off = 32; off > 0; off >>= 1) m = fmaxf(m, __shfl_down(m, off, 64));
    __shared__ float sm[16];
    int wave = threadIdx.x >> 6;
    if ((threadIdx.x & 63) == 0) sm[wave] = m;
    __syncthreads();
    if (threadIdx.x == 0) {
        int nw = blockDim.x >> 6;
        float mm = sm[0];
        for (int i = 1; i < nw; ++i) mm = fmaxf(mm, sm[i]);
        vmax[bc] = mm;
    }
}

__global__ void norm_kernel(float* __restrict__ out, const float* __restrict__ vmax) {
    const int bc = blockIdx.y;
    const float inv = 1.0f / vmax[bc];
    float4* p = reinterpret_cast<float4*>(out + (size_t)bc * HIST);
    int i = blockIdx.x * blockDim.x + threadIdx.x;
    float4 v = p[i];
    v.x *= inv; v.y *= inv; v.z *= inv; v.w *= inv;
    p[i] = v;
}

extern "C" void kernel_launch(void* const* d_in, const int* in_sizes, int n_in,
                              void* d_out, int out_size, void* d_ws, size_t ws_size,
                              hipStream_t stream) {
    const float* X = (const float*)d_in[0];
    float* out = (float*)d_out;
    float* vmax = (float*)d_ws;

    // d_out is poisoned 0xAA before every launch -> zero it (float4 stores).
    // out_size = 96*65536 = 6291456 floats -> 1572864 float4 -> 6144 blocks of 256.
    zero_kernel<<<dim3(6144), 256, 0, stream>>>(out);

    // Histogram accumulate: grid (64, 96), 256 thr, each thread strides float4-pairs.
    hist_kernel<<<dim3(64, NIMG), 256, 0, stream>>>(X, out);

    // Per-image max of 65536 bins.
    max_kernel<<<NIMG, 256, 0, stream>>>(out, vmax);

    // Normalize: 64 blocks x 256 thr x float4 = 65536 elems per image.
    norm_kernel<<<dim3(64, NIMG), 256, 0, stream>>>(out, vmax);
}

// Round 2
// 859.395 us; speedup vs baseline: 5.7786x; 5.7786x over previous
//
#include <hip/hip_runtime.h>

#define NBINS 256
constexpr int W_IMG = 512;
constexpr int H_IMG = 512;
constexpr int IMG_ELEMS = H_IMG * W_IMG;          // 262144
constexpr int PAIRS = (H_IMG - 1) * W_IMG;        // 261632
constexpr int PAIRS4 = PAIRS / 4;                 // 65408
constexpr int NIMG = 96;
constexpr int HIST = NBINS * NBINS;               // 65536
constexpr int GROUPS = 4;
constexpr int GROUP_ROWS = NBINS / GROUPS;        // 64 rows -> 64 KB LDS

// cos(pi*d) for d in [0,1): v_cos_f32 takes revolutions -> cos(2*pi*x), so x = d/2.
__device__ __forceinline__ float cospi_fast(float d) {
    return __builtin_amdgcn_cosf(0.5f * d);
}

// One block per (row-group, image). LDS-private 64x256 sub-histogram, full-image
// scan with predicated LDS atomics, conflict-free float4 writeback (no global
// atomics, no zero pass needed: every output bin owned by exactly one block).
__global__ __launch_bounds__(256) void hist_kernel(const float* __restrict__ X,
                                                   float* __restrict__ out) {
    __shared__ float lh[GROUP_ROWS * NBINS];
    const int bc = blockIdx.y;
    const int lo = blockIdx.x * GROUP_ROWS;
    const float* img = X + (size_t)bc * IMG_ELEMS;

    for (int i = threadIdx.x; i < GROUP_ROWS * NBINS; i += 256) lh[i] = 0.0f;
    __syncthreads();

    for (int k4 = threadIdx.x; k4 < PAIRS4; k4 += 256) {
        float4 av = reinterpret_cast<const float4*>(img)[k4];
        float4 bv = reinterpret_cast<const float4*>(img + W_IMG)[k4];
        const float* ap = &av.x;
        const float* bp = &bv.x;
#pragma unroll
        for (int j = 0; j < 4; ++j) {
            float a = ap[j];
            float b = bp[j];
            float fa = fminf(floorf(a), 255.0f);
            float fb = fminf(floorf(b), 255.0f);
            float da = a - fa, db = b - fb;
            float wa0 = 0.5f + 0.5f * cospi_fast(da);
            float wb0 = 0.5f + 0.5f * cospi_fast(db);
            float wa1 = 1.0f - wa0, wb1 = 1.0f - wb0;
            int ia0 = (int)fa, ib0 = (int)fb;
            int ia1 = min(ia0 + 1, NBINS - 1);
            int ib1 = min(ib0 + 1, NBINS - 1);
            int ra0 = ia0 - lo;
            int ra1 = ia1 - lo;
            if ((unsigned)ra0 < (unsigned)GROUP_ROWS) {
                atomicAdd(&lh[ra0 * NBINS + ib0], wa0 * wb0);
                atomicAdd(&lh[ra0 * NBINS + ib1], wa0 * wb1);
            }
            if ((unsigned)ra1 < (unsigned)GROUP_ROWS) {
                atomicAdd(&lh[ra1 * NBINS + ib0], wa1 * wb0);
                atomicAdd(&lh[ra1 * NBINS + ib1], wa1 * wb1);
            }
        }
    }
    __syncthreads();

    float* ho = out + (size_t)bc * HIST + (size_t)lo * NBINS;
    const float4* src = reinterpret_cast<const float4*>(lh);
    float4* dst = reinterpret_cast<float4*>(ho);
    for (int i = threadIdx.x; i < GROUP_ROWS * NBINS / 4; i += 256) dst[i] = src[i];
}

__global__ void max_kernel(const float* __restrict__ out, float* __restrict__ vmax) {
    const int bc = blockIdx.x;
    const float* h = out + (size_t)bc * HIST;
    float m = 0.0f;
    for (int i = threadIdx.x; i < HIST; i += blockDim.x) m = fmaxf(m, h[i]);
#pragma unroll
    for (int off = 32; off > 0; off >>= 1) m = fmaxf(m, __shfl_down(m, off, 64));
    __shared__ float sm[16];
    int wave = threadIdx.x >> 6;
    if ((threadIdx.x & 63) == 0) sm[wave] = m;
    __syncthreads();
    if (threadIdx.x == 0) {
        int nw = blockDim.x >> 6;
        float mm = sm[0];
        for (int i = 1; i < nw; ++i) mm = fmaxf(mm, sm[i]);
        vmax[bc] = mm;
    }
}

__global__ void norm_kernel(float* __restrict__ out, const float* __restrict__ vmax) {
    const int bc = blockIdx.y;
    const float inv = 1.0f / vmax[bc];
    float4* p = reinterpret_cast<float4*>(out + (size_t)bc * HIST);
    int i = blockIdx.x * blockDim.x + threadIdx.x;
    float4 v = p[i];
    v.x *= inv; v.y *= inv; v.z *= inv; v.w *= inv;
    p[i] = v;
}

extern "C" void kernel_launch(void* const* d_in, const int* in_sizes, int n_in,
                              void* d_out, int out_size, void* d_ws, size_t ws_size,
                              hipStream_t stream) {
    const float* X = (const float*)d_in[0];
    float* out = (float*)d_out;
    float* vmax = (float*)d_ws;

    // Histogram: grid (4 row-groups, 96 images), 256 thr, 64 KB LDS each.
    hist_kernel<<<dim3(GROUPS, NIMG), 256, 0, stream>>>(X, out);

    // Per-image max of 65536 bins.
    max_kernel<<<NIMG, 256, 0, stream>>>(out, vmax);

    // Normalize: 64 blocks x 256 thr x float4 = 65536 elems per image.
    norm_kernel<<<dim3(64, NIMG), 256, 0, stream>>>(out, vmax);
}

// Round 3
// 287.718 us; speedup vs baseline: 17.2603x; 2.9869x over previous
//
#include <hip/hip_runtime.h>

#define NBINS 256
constexpr int W_IMG = 512;
constexpr int H_IMG = 512;
constexpr int IMG_ELEMS = H_IMG * W_IMG;          // 262144
constexpr int PAIRS = (H_IMG - 1) * W_IMG;        // 261632
constexpr int PAIRS4 = PAIRS / 4;                 // 65408
constexpr int NIMG = 96;
constexpr int HIST = NBINS * NBINS;               // 65536
constexpr int GROUPS = 4;
constexpr int GROUP_ROWS = NBINS / GROUPS;        // 64 rows
constexpr int LDSW = GROUP_ROWS * (NBINS / 2);    // 8192 u32 words = 32 KB
constexpr float QSCALE = 1024.0f;                 // 2^-10 fixed point in u16 halves
constexpr float INVQ = 1.0f / 1024.0f;

// cos(pi*d): v_cos_f32 takes revolutions -> cos(2*pi*x), x = d/2 in [0,0.5] (no reduction needed).
__device__ __forceinline__ float cospi_fast(float d) {
    return __builtin_amdgcn_cosf(0.5f * d);
}

// One block per (row-group, image, slice). 32 KB LDS u16-packed sub-histogram:
// word w = bins (2c, 2c+1) of row r, r = w>>7, c = w&127. Branchless gating
// (out-of-group rows add quantized 0), plain-store writeback (disjoint per slice),
// fused block-local max -> partial[].
__global__ __launch_bounds__(512, 6)
void hist_kernel(const float* __restrict__ X, float* __restrict__ out0,
                 float* __restrict__ out1, float* __restrict__ partial) {
    __shared__ unsigned int lh[LDSW];
    const int tid = threadIdx.x;
    const int bc = blockIdx.y;
    const int lo = blockIdx.x * GROUP_ROWS;
    const float* img = X + (size_t)bc * IMG_ELEMS;

    for (int i = tid; i < LDSW; i += 512) lh[i] = 0u;
    __syncthreads();

    const int per = PAIRS4 / gridDim.z;               // 65408 (S=1) or 32704 (S=2)
    const int beg = blockIdx.z * per;
    const int end = beg + per;
    for (int k4 = beg + tid; k4 < end; k4 += 512) {
        float4 av = reinterpret_cast<const float4*>(img)[k4];
        float4 bv = reinterpret_cast<const float4*>(img + W_IMG)[k4];
        const float* ap = &av.x;
        const float* bp = &bv.x;
#pragma unroll
        for (int j = 0; j < 4; ++j) {
            float a = ap[j];
            float b = bp[j];
            float fa = fminf(floorf(a), 255.0f);
            float fb = fminf(floorf(b), 255.0f);
            float wa0 = 0.5f + 0.5f * cospi_fast(a - fa);
            float wb0 = 0.5f + 0.5f * cospi_fast(b - fb);
            float wa1 = 1.0f - wa0, wb1 = 1.0f - wb0;
            int ia0 = (int)fa, ib0 = (int)fb;
            int ia1 = min(ia0 + 1, NBINS - 1);
            int ib1 = min(ib0 + 1, NBINS - 1);
            int r0 = ia0 - lo, r1 = ia1 - lo;
            // gate: out-of-group row -> quantizes to 0 (branchless, no exec-mask churn)
            float g0 = ((unsigned)r0 < (unsigned)GROUP_ROWS) ? QSCALE : 0.0f;
            float g1 = ((unsigned)r1 < (unsigned)GROUP_ROWS) ? QSCALE : 0.0f;
            unsigned q00 = (unsigned)(wa0 * wb0 * g0 + 0.5f);
            unsigned q01 = (unsigned)(wa0 * wb1 * g0 + 0.5f);
            unsigned q10 = (unsigned)(wa1 * wb0 * g1 + 0.5f);
            unsigned q11 = (unsigned)(wa1 * wb1 * g1 + 0.5f);
            unsigned c0 = (unsigned)ib0 >> 1, sh0 = ((unsigned)ib0 & 1u) << 4;
            unsigned c1 = (unsigned)ib1 >> 1, sh1 = ((unsigned)ib1 & 1u) << 4;
            unsigned rb0 = ((unsigned)r0 & 63u) << 7;
            unsigned rb1 = ((unsigned)r1 & 63u) << 7;
            atomicAdd(&lh[rb0 + c0], q00 << sh0);
            atomicAdd(&lh[rb0 + c1], q01 << sh1);
            atomicAdd(&lh[rb1 + c0], q10 << sh0);
            atomicAdd(&lh[rb1 + c1], q11 << sh1);
        }
    }
    __syncthreads();

    // Writeback (float2 per word, fully coalesced) + local max.
    float* dst = (blockIdx.z == 0) ? out0 : out1;
    float* ho = dst + (size_t)bc * HIST + (size_t)lo * NBINS;
    float m = 0.0f;
    for (int i = tid; i < LDSW; i += 512) {
        unsigned w = lh[i];
        float v0 = (float)(w & 0xFFFFu) * INVQ;
        float v1 = (float)(w >> 16) * INVQ;
        reinterpret_cast<float2*>(ho)[i] = make_float2(v0, v1);
        m = fmaxf(m, fmaxf(v0, v1));
    }
    __syncthreads();  // all lh reads done before reuse as reduce scratch
#pragma unroll
    for (int off = 32; off > 0; off >>= 1) m = fmaxf(m, __shfl_down(m, off, 64));
    float* red = reinterpret_cast<float*>(lh);
    if ((tid & 63) == 0) red[tid >> 6] = m;
    __syncthreads();
    if (tid == 0) {
        float mm = red[0];
#pragma unroll
        for (int i = 1; i < 8; ++i) mm = fmaxf(mm, red[i]);
        partial[blockIdx.z * (GROUPS * NIMG) + bc * GROUPS + blockIdx.x] = mm;
    }
}

// S=2 only: out += ws slice, per-quarter max -> partial[0..383] (overwrites hist's).
__global__ __launch_bounds__(256)
void mergemax_kernel(float* __restrict__ out, const float* __restrict__ ws1,
                     float* __restrict__ partial) {
    const int b = blockIdx.x;                 // b = bc*4 + quarter
    const size_t base = (size_t)b * (HIST / 4);
    float4* o = reinterpret_cast<float4*>(out + base);
    const float4* w = reinterpret_cast<const float4*>(ws1 + base);
    float m = 0.0f;
    for (int i = threadIdx.x; i < HIST / 16; i += 256) {
        float4 x = o[i];
        float4 y = w[i];
        x.x += y.x; x.y += y.y; x.z += y.z; x.w += y.w;
        o[i] = x;
        m = fmaxf(m, fmaxf(fmaxf(x.x, x.y), fmaxf(x.z, x.w)));
    }
#pragma unroll
    for (int off = 32; off > 0; off >>= 1) m = fmaxf(m, __shfl_down(m, off, 64));
    __shared__ float sm[4];
    if ((threadIdx.x & 63) == 0) sm[threadIdx.x >> 6] = m;
    __syncthreads();
    if (threadIdx.x == 0) {
        float mm = fmaxf(fmaxf(sm[0], sm[1]), fmaxf(sm[2], sm[3]));
        partial[b] = mm;
    }
}

__global__ void norm_kernel(float* __restrict__ out, const float* __restrict__ partial) {
    const int bc = blockIdx.y;
    const float vm = fmaxf(fmaxf(partial[bc * 4 + 0], partial[bc * 4 + 1]),
                           fmaxf(partial[bc * 4 + 2], partial[bc * 4 + 3]));
    const float inv = 1.0f / vm;
    float4* p = reinterpret_cast<float4*>(out + (size_t)bc * HIST);
    int i = blockIdx.x * blockDim.x + threadIdx.x;
    float4 v = p[i];
    v.x *= inv; v.y *= inv; v.z *= inv; v.w *= inv;
    p[i] = v;
}

extern "C" void kernel_launch(void* const* d_in, const int* in_sizes, int n_in,
                              void* d_out, int out_size, void* d_ws, size_t ws_size,
                              hipStream_t stream) {
    const float* X = (const float*)d_in[0];
    float* out = (float*)d_out;

    const size_t slice_bytes = (size_t)NIMG * HIST * sizeof(float);  // 24 MB
    const int nsl = (ws_size >= slice_bytes + 4096) ? 2 : 1;         // constant per deploy

    float* ws1 = (float*)d_ws;
    float* partial = (nsl == 2) ? (float*)((char*)d_ws + slice_bytes)
                                : (float*)d_ws;

    // Histogram: (4 groups, 96 images, nsl slices), 512 thr, 32 KB LDS.
    hist_kernel<<<dim3(GROUPS, NIMG, nsl), 512, 0, stream>>>(X, out, ws1, partial);

    if (nsl == 2)
        mergemax_kernel<<<dim3(GROUPS * NIMG), 256, 0, stream>>>(out, ws1, partial);

    // Normalize: 64 blocks x 256 thr x float4 per image.
    norm_kernel<<<dim3(64, NIMG), 256, 0, stream>>>(out, partial);
}

// Round 4
// 277.336 us; speedup vs baseline: 17.9064x; 1.0374x over previous
//
#include <hip/hip_runtime.h>

#define NBINS 256
constexpr int W_IMG = 512;
constexpr int H_IMG = 512;
constexpr int IMG_ELEMS = H_IMG * W_IMG;          // 262144
constexpr int PAIR_ROWS = H_IMG - 1;              // 511
constexpr int NIMG = 96;
constexpr int HIST = NBINS * NBINS;               // 65536
constexpr int GROUPS = 2;
constexpr int GROUP_ROWS = NBINS / GROUPS;        // 128 rows per group
constexpr int LDSW = GROUP_ROWS * (NBINS / 2);    // 16384 u32 words = 64 KB
constexpr int WORDS_PER_IMG = HIST / 2;           // 32768 packed words per image
constexpr int QI = 1024;                          // fixed-point scale (proven in R2)
constexpr float QSCALE = 1024.0f;
constexpr float INVQ = 1.0f / 1024.0f;

// cos(pi*d): v_cos_f32 takes revolutions -> cos(2*pi*x), x = d/2 in [0,0.5].
__device__ __forceinline__ float cospi_fast(float d) {
    return __builtin_amdgcn_cosf(0.5f * d);
}

struct QElem {
    int i0;        // floor bin (0..254, input < 255 guaranteed)
    int q0, q1;    // b-role weights, q0+q1 = 1024
    int ga0, ga1;  // a-role weights gated to this block's row group (0 if outside)
    unsigned r0, r1;  // (i0-lo)&127, (i0+1-lo)&127 (aliased rows receive +0)
};

__device__ __forceinline__ QElem quantize(float x, int lo) {
    QElem e;
    float fa = floorf(x);
    float w0 = 0.5f + 0.5f * cospi_fast(x - fa);
    e.i0 = (int)fa;
    e.q0 = (int)(w0 * QSCALE + 0.5f);
    e.q1 = QI - e.q0;
    int r0 = e.i0 - lo;
    e.ga0 = ((unsigned)r0 < (unsigned)GROUP_ROWS) ? e.q0 : 0;
    e.ga1 = ((unsigned)(r0 + 1) < (unsigned)GROUP_ROWS) ? e.q1 : 0;
    e.r0 = (unsigned)r0 & (GROUP_ROWS - 1);
    e.r1 = (unsigned)(r0 + 1) & (GROUP_ROWS - 1);
    return e;
}

// Block (g, bc, s): rows [beg,end) of image bc, gated to a-bin rows [g*128,(g+1)*128).
// Thread t owns column t; rows walked sequentially so each element is quantized
// exactly once (register-carried to the next pair). u16-packed LDS sub-histogram,
// raw u32 writeback to ws (disjoint per slice, no global atomics, no zero pass).
__global__ __launch_bounds__(512, 4)
void hist_kernel(const float* __restrict__ X, unsigned* __restrict__ ws) {
    __shared__ unsigned lh[LDSW];
    const int tid = threadIdx.x;
    const int g = blockIdx.x;
    const int bc = blockIdx.y;
    const int s = blockIdx.z;
    const int S = gridDim.z;
    const int lo = g * GROUP_ROWS;
    const float* col = X + (size_t)bc * IMG_ELEMS + tid;

    {
        uint4* lv = reinterpret_cast<uint4*>(lh);
        for (int i = tid; i < LDSW / 4; i += 512) lv[i] = make_uint4(0u, 0u, 0u, 0u);
    }
    __syncthreads();

    const int r_beg = (PAIR_ROWS * s) / S;
    const int r_end = (PAIR_ROWS * (s + 1)) / S;

    float vnext = col[(size_t)(r_beg + 1) * W_IMG];
    QElem a = quantize(col[(size_t)r_beg * W_IMG], lo);
    for (int pr = r_beg; pr < r_end; ++pr) {
        float v = vnext;
        if (pr + 2 <= r_end) vnext = col[(size_t)(pr + 2) * W_IMG];  // prefetch
        QElem b = quantize(v, lo);
        // products of u16 weights, rounded back to scale 1024
        unsigned p00 = (unsigned)(a.ga0 * b.q0 + QI / 2) >> 10;
        unsigned p01 = (unsigned)(a.ga0 * b.q1 + QI / 2) >> 10;
        unsigned p10 = (unsigned)(a.ga1 * b.q0 + QI / 2) >> 10;
        unsigned p11 = (unsigned)(a.ga1 * b.q1 + QI / 2) >> 10;
        unsigned c0 = (unsigned)b.i0 >> 1;
        unsigned c1 = (unsigned)(b.i0 + 1) >> 1;
        unsigned sh0 = ((unsigned)b.i0 & 1u) << 4;
        unsigned sh1 = sh0 ^ 16u;
        atomicAdd(&lh[a.r0 * (NBINS / 2) + c0], p00 << sh0);
        atomicAdd(&lh[a.r0 * (NBINS / 2) + c1], p01 << sh1);
        atomicAdd(&lh[a.r1 * (NBINS / 2) + c0], p10 << sh0);
        atomicAdd(&lh[a.r1 * (NBINS / 2) + c1], p11 << sh1);
        a = b;
    }
    __syncthreads();

    // Raw u32 writeback: ws[s][bc][g*16384 + w], coalesced uint4.
    unsigned* dst = ws + ((size_t)s * NIMG + bc) * WORDS_PER_IMG + (size_t)g * LDSW;
    const uint4* sv = reinterpret_cast<const uint4*>(lh);
    uint4* dv = reinterpret_cast<uint4*>(dst);
    for (int i = tid; i < LDSW / 4; i += 512) dv[i] = sv[i];
}

// Sum S slices (whole-u32 add: u16 halves can't carry, max bin << 65535),
// dequantize to f32 out, fused per-block max -> partial[bc*32 + bx].
__global__ __launch_bounds__(256)
void merge_kernel(const unsigned* __restrict__ ws, float* __restrict__ out,
                  float* __restrict__ partial, int S) {
    const int bc = blockIdx.y;
    const int W0 = blockIdx.x * 1024;
    float2* o = reinterpret_cast<float2*>(out + (size_t)bc * HIST);
    float m = 0.0f;
    for (int i = threadIdx.x; i < 1024; i += 256) {
        const int W = W0 + i;
        unsigned sum = 0u;
        for (int s = 0; s < S; ++s)
            sum += ws[((size_t)s * NIMG + bc) * WORDS_PER_IMG + W];
        float v0 = (float)(sum & 0xFFFFu) * INVQ;
        float v1 = (float)(sum >> 16) * INVQ;
        o[W] = make_float2(v0, v1);
        m = fmaxf(m, fmaxf(v0, v1));
    }
#pragma unroll
    for (int off = 32; off > 0; off >>= 1) m = fmaxf(m, __shfl_down(m, off, 64));
    __shared__ float sm[4];
    if ((threadIdx.x & 63) == 0) sm[threadIdx.x >> 6] = m;
    __syncthreads();
    if (threadIdx.x == 0)
        partial[bc * 32 + blockIdx.x] = fmaxf(fmaxf(sm[0], sm[1]), fmaxf(sm[2], sm[3]));
}

__global__ void norm_kernel(float* __restrict__ out, const float* __restrict__ partial) {
    const int bc = blockIdx.y;
    float vm = 0.0f;
#pragma unroll
    for (int i = 0; i < 32; ++i) vm = fmaxf(vm, partial[bc * 32 + i]);
    const float inv = 1.0f / vm;
    float4* p = reinterpret_cast<float4*>(out + (size_t)bc * HIST);
    int i = blockIdx.x * blockDim.x + threadIdx.x;
    float4 v = p[i];
    v.x *= inv; v.y *= inv; v.z *= inv; v.w *= inv;
    p[i] = v;
}

extern "C" void kernel_launch(void* const* d_in, const int* in_sizes, int n_in,
                              void* d_out, int out_size, void* d_ws, size_t ws_size,
                              hipStream_t stream) {
    const float* X = (const float*)d_in[0];
    float* out = (float*)d_out;

    const size_t slice_bytes = (size_t)NIMG * WORDS_PER_IMG * sizeof(unsigned);  // 12 MB
    int S = 4;
    while (S > 1 && ws_size < (size_t)S * slice_bytes + 16384) S >>= 1;

    unsigned* ws = (unsigned*)d_ws;
    float* partial = (float*)((char*)d_ws + (size_t)S * slice_bytes);

    // Histogram: (2 groups, 96 images, S slices), 512 thr, 64 KB LDS, 2 blocks/CU.
    hist_kernel<<<dim3(GROUPS, NIMG, S), 512, 0, stream>>>(X, ws);

    // Merge slices + dequant + per-block max: (32, 96) x 256 thr.
    merge_kernel<<<dim3(32, NIMG), 256, 0, stream>>>(ws, out, partial, S);

    // Normalize: (64, 96) x 256 thr x float4.
    norm_kernel<<<dim3(64, NIMG), 256, 0, stream>>>(out, partial);
}

// Round 5
// 202.793 us; speedup vs baseline: 24.4886x; 1.3676x over previous
//
#include <hip/hip_runtime.h>

#define NBINS 256
constexpr int W_IMG = 512;
constexpr int H_IMG = 512;
constexpr int IMG_ELEMS = H_IMG * W_IMG;          // 262144
constexpr int PAIR_ROWS = H_IMG - 1;              // 511
constexpr int NIMG = 96;
constexpr int HIST = NBINS * NBINS;               // 65536
constexpr int GROUPS = 2;
constexpr int GROUP_ROWS = NBINS / GROUPS;        // 128 rows per group
constexpr int LDSW = GROUP_ROWS * (NBINS / 2);    // 16384 u32 words = 64 KB
constexpr int WORDS_PER_IMG = HIST / 2;           // 32768 packed words per image
constexpr int QI = 1024;                          // fixed-point scale
constexpr float QSCALE = 1024.0f;
constexpr float INVQ = 1.0f / 1024.0f;
constexpr int PF = 8;                             // prefetch ring depth

// cos(pi*d): v_cos_f32 takes revolutions -> cos(2*pi*x), x = d/2 in [0,0.5].
__device__ __forceinline__ float cospi_fast(float d) {
    return __builtin_amdgcn_cosf(0.5f * d);
}

struct QElem {
    int i0;        // floor bin (input in [0,255))
    int q0, q1;    // b-role weights, q0+q1 = 1024
    int ga0, ga1;  // a-role weights gated to this block's row group (0 if outside)
    unsigned r0, r1;  // gated row indices (aliased rows receive +0)
};

__device__ __forceinline__ QElem quantize(float x, int lo) {
    QElem e;
    float fa = floorf(x);
    float w0 = 0.5f + 0.5f * cospi_fast(x - fa);
    e.i0 = (int)fa;
    e.q0 = (int)(w0 * QSCALE + 0.5f);
    e.q1 = QI - e.q0;
    int r0 = e.i0 - lo;
    e.ga0 = ((unsigned)r0 < (unsigned)GROUP_ROWS) ? e.q0 : 0;
    e.ga1 = ((unsigned)(r0 + 1) < (unsigned)GROUP_ROWS) ? e.q1 : 0;
    e.r0 = (unsigned)r0 & (GROUP_ROWS - 1);
    e.r1 = (unsigned)(r0 + 1) & (GROUP_ROWS - 1);
    return e;
}

// Block (g, bc, s): pair-rows [r_beg,r_end) of image bc, a-rows gated to
// [g*128,(g+1)*128). Thread t owns column t; rows walked in batches of 8 with a
// depth-8 register prefetch ring (8 coalesced loads in flight per wave) so
// L3/HBM latency is hidden. Lanes whose pair is entirely outside the row group
// skip the products + 4 LDS atomics (exec-mask divergence, ~halves LDS lane-ops).
__global__ __launch_bounds__(512, 4)
void hist_kernel(const float* __restrict__ X, unsigned* __restrict__ ws) {
    __shared__ unsigned lh[LDSW];
    const int tid = threadIdx.x;
    const int g = blockIdx.x;
    const int bc = blockIdx.y;
    const int s = blockIdx.z;
    const int S = gridDim.z;
    const int lo = g * GROUP_ROWS;
    const float* col = X + (size_t)bc * IMG_ELEMS + tid;

    {
        uint4* lv = reinterpret_cast<uint4*>(lh);
        for (int i = tid; i < LDSW / 4; i += 512) lv[i] = make_uint4(0u, 0u, 0u, 0u);
    }
    __syncthreads();

    const int r_beg = (PAIR_ROWS * s) / S;
    const int r_end = (PAIR_ROWS * (s + 1)) / S;

    float cur[PF], nxt[PF];
#pragma unroll
    for (int j = 0; j < PF; ++j)
        cur[j] = col[(size_t)min(r_beg + 1 + j, H_IMG - 1) * W_IMG];
    QElem a = quantize(col[(size_t)r_beg * W_IMG], lo);

    for (int R = r_beg; R < r_end; R += PF) {
#pragma unroll
        for (int j = 0; j < PF; ++j)
            nxt[j] = col[(size_t)min(R + PF + 1 + j, H_IMG - 1) * W_IMG];
#pragma unroll
        for (int j = 0; j < PF; ++j) {
            if (R + j < r_end) {                    // scalar guard (r_end uniform)
                QElem b = quantize(cur[j], lo);
                if (a.ga0 | a.ga1) {                // skip: pair outside this row group
                    unsigned p00 = (unsigned)(a.ga0 * b.q0 + QI / 2) >> 10;
                    unsigned p01 = (unsigned)(a.ga0 * b.q1 + QI / 2) >> 10;
                    unsigned p10 = (unsigned)(a.ga1 * b.q0 + QI / 2) >> 10;
                    unsigned p11 = (unsigned)(a.ga1 * b.q1 + QI / 2) >> 10;
                    unsigned c0 = (unsigned)b.i0 >> 1;
                    unsigned c1 = (unsigned)(b.i0 + 1) >> 1;
                    unsigned sh0 = ((unsigned)b.i0 & 1u) << 4;
                    unsigned sh1 = sh0 ^ 16u;
                    atomicAdd(&lh[a.r0 * (NBINS / 2) + c0], p00 << sh0);
                    atomicAdd(&lh[a.r0 * (NBINS / 2) + c1], p01 << sh1);
                    atomicAdd(&lh[a.r1 * (NBINS / 2) + c0], p10 << sh0);
                    atomicAdd(&lh[a.r1 * (NBINS / 2) + c1], p11 << sh1);
                }
                a = b;
            }
        }
#pragma unroll
        for (int j = 0; j < PF; ++j) cur[j] = nxt[j];
    }
    __syncthreads();

    // Raw u32 writeback: ws[s][bc][g*16384 + w], coalesced uint4.
    unsigned* dst = ws + ((size_t)s * NIMG + bc) * WORDS_PER_IMG + (size_t)g * LDSW;
    const uint4* sv = reinterpret_cast<const uint4*>(lh);
    uint4* dv = reinterpret_cast<uint4*>(dst);
    for (int i = tid; i < LDSW / 4; i += 512) dv[i] = sv[i];
}

// Sum S slices (whole-u32 add: u16 halves can't carry, max bin << 65535),
// dequantize to f32 out, fused per-block max -> partial[bc*32 + bx].
__global__ __launch_bounds__(256)
void merge_kernel(const unsigned* __restrict__ ws, float* __restrict__ out,
                  float* __restrict__ partial, int S) {
    const int bc = blockIdx.y;
    const int W0 = blockIdx.x * 1024;
    float2* o = reinterpret_cast<float2*>(out + (size_t)bc * HIST);
    float m = 0.0f;
    for (int i = threadIdx.x; i < 1024; i += 256) {
        const int W = W0 + i;
        unsigned sum = 0u;
        for (int s = 0; s < S; ++s)
            sum += ws[((size_t)s * NIMG + bc) * WORDS_PER_IMG + W];
        float v0 = (float)(sum & 0xFFFFu) * INVQ;
        float v1 = (float)(sum >> 16) * INVQ;
        o[W] = make_float2(v0, v1);
        m = fmaxf(m, fmaxf(v0, v1));
    }
#pragma unroll
    for (int off = 32; off > 0; off >>= 1) m = fmaxf(m, __shfl_down(m, off, 64));
    __shared__ float sm[4];
    if ((threadIdx.x & 63) == 0) sm[threadIdx.x >> 6] = m;
    __syncthreads();
    if (threadIdx.x == 0)
        partial[bc * 32 + blockIdx.x] = fmaxf(fmaxf(sm[0], sm[1]), fmaxf(sm[2], sm[3]));
}

__global__ void norm_kernel(float* __restrict__ out, const float* __restrict__ partial) {
    const int bc = blockIdx.y;
    float vm = 0.0f;
#pragma unroll
    for (int i = 0; i < 32; ++i) vm = fmaxf(vm, partial[bc * 32 + i]);
    const float inv = 1.0f / vm;
    float4* p = reinterpret_cast<float4*>(out + (size_t)bc * HIST);
    int i = blockIdx.x * blockDim.x + threadIdx.x;
    float4 v = p[i];
    v.x *= inv; v.y *= inv; v.z *= inv; v.w *= inv;
    p[i] = v;
}

extern "C" void kernel_launch(void* const* d_in, const int* in_sizes, int n_in,
                              void* d_out, int out_size, void* d_ws, size_t ws_size,
                              hipStream_t stream) {
    const float* X = (const float*)d_in[0];
    float* out = (float*)d_out;

    const size_t slice_bytes = (size_t)NIMG * WORDS_PER_IMG * sizeof(unsigned);  // 12 MB
    int S = 4;
    while (S > 1 && ws_size < (size_t)S * slice_bytes + 16384) S >>= 1;

    unsigned* ws = (unsigned*)d_ws;
    float* partial = (float*)((char*)d_ws + (size_t)S * slice_bytes);

    // Histogram: (2 groups, 96 images, S slices), 512 thr, 64 KB LDS, 2 blocks/CU.
    hist_kernel<<<dim3(GROUPS, NIMG, S), 512, 0, stream>>>(X, ws);

    // Merge slices + dequant + per-block max: (32, 96) x 256 thr.
    merge_kernel<<<dim3(32, NIMG), 256, 0, stream>>>(ws, out, partial, S);

    // Normalize: (64, 96) x 256 thr x float4.
    norm_kernel<<<dim3(64, NIMG), 256, 0, stream>>>(out, partial);
}

// Round 7
// 194.374 us; speedup vs baseline: 25.5493x; 1.0433x over previous
//
#include <hip/hip_runtime.h>

#define NBINS 256
constexpr int W_IMG = 512;
constexpr int H_IMG = 512;
constexpr int IMG_ELEMS = H_IMG * W_IMG;          // 262144
constexpr int PAIR_ROWS = H_IMG - 1;              // 511
constexpr int NIMG = 96;
constexpr int HIST = NBINS * NBINS;               // 65536
constexpr int WORDS_PER_IMG = HIST / 2;           // 32768 packed u32 = 128 KB
constexpr int QI = 1024;                          // fixed-point scale (validated R2-R4)
constexpr int PF = 8;                             // prefetch ring depth

// cos(pi*d): v_cos_f32 takes revolutions -> cos(2*pi*x), x = d/2 in [0,0.5].
__device__ __forceinline__ float cospi_fast(float d) {
    return __builtin_amdgcn_cosf(0.5f * d);
}

struct Q { int i0, q0; };  // floor bin, w0 quantized to 1024

__device__ __forceinline__ Q quant(float x) {
    float fa = floorf(x);
    Q e;
    e.i0 = (int)fa;
    // round(1024*(0.5+0.5*cos)) = trunc(512*cos + 512.5), value >= 0
    e.q0 = (int)(cospi_fast(x - fa) * 512.0f + 512.5f);
    return e;
}

// ---------- primary: GROUPS=1, full 128 KB dynamic-LDS histogram ----------
// Block (s, bc): pair-rows [rb,re) of image bc into a whole-image u16-packed
// hist. 1024 threads: col = tid&511, sub = tid>>9 halves the row range (waves
// are sub-uniform). Depth-8 register prefetch ring hides L3/HBM latency.
// Each element quantized exactly ONCE chip-wide (vs 2x in the 2-group scheme).
__global__ __launch_bounds__(1024, 4)
void hist1_kernel(const float* __restrict__ X, unsigned* __restrict__ ws) {
    extern __shared__ unsigned lh[];              // 32768 words = 128 KB
    const int tid = threadIdx.x;
    const int s = blockIdx.x;
    const int bc = blockIdx.y;
    const int S = gridDim.x;
    const float* col = X + (size_t)bc * IMG_ELEMS + (tid & (W_IMG - 1));

    {
        uint4* lv = reinterpret_cast<uint4*>(lh);
        for (int i = tid; i < WORDS_PER_IMG / 4; i += 1024)
            lv[i] = make_uint4(0u, 0u, 0u, 0u);
    }
    __syncthreads();

    const int rb = (PAIR_ROWS * s) / S;
    const int re = (PAIR_ROWS * (s + 1)) / S;
    const int l0 = (re - rb + 1) >> 1;
    const int sub = tid >> 9;
    const int r0t = rb + sub * l0;
    const int r1t = sub ? re : rb + l0;

    float cur[PF], nxt[PF];
#pragma unroll
    for (int j = 0; j < PF; ++j)
        cur[j] = col[(size_t)min(r0t + 1 + j, PAIR_ROWS) * W_IMG];
    Q a = quant(col[(size_t)r0t * W_IMG]);

    for (int R = r0t; R < r1t; R += PF) {
#pragma unroll
        for (int j = 0; j < PF; ++j)
            nxt[j] = col[(size_t)min(R + PF + 1 + j, PAIR_ROWS) * W_IMG];
#pragma unroll
        for (int j = 0; j < PF; ++j) {
            if (R + j < r1t) {                    // wave-uniform (sub-homogeneous)
                Q b = quant(cur[j]);
                int qa1 = QI - a.q0, qb1 = QI - b.q0;
                unsigned p00 = (unsigned)(a.q0 * b.q0 + QI / 2) >> 10;
                unsigned p01 = (unsigned)(a.q0 * qb1 + QI / 2) >> 10;
                unsigned p10 = (unsigned)(qa1 * b.q0 + QI / 2) >> 10;
                unsigned p11 = (unsigned)(qa1 * qb1 + QI / 2) >> 10;
                unsigned c0 = (unsigned)b.i0 >> 1;
                unsigned c1 = (unsigned)(b.i0 + 1) >> 1;
                unsigned sh0 = ((unsigned)b.i0 & 1u) << 4;
                unsigned sh1 = sh0 ^ 16u;
                unsigned base0 = (unsigned)a.i0 << 7;        // row * 128 words
                unsigned base1 = base0 + 128u;               // i0 <= 254 -> in range
                atomicAdd(&lh[base0 + c0], p00 << sh0);
                atomicAdd(&lh[base0 + c1], p01 << sh1);
                atomicAdd(&lh[base1 + c0], p10 << sh0);
                atomicAdd(&lh[base1 + c1], p11 << sh1);
                a = b;
            }
        }
#pragma unroll
        for (int j = 0; j < PF; ++j) cur[j] = nxt[j];
    }
    __syncthreads();

    unsigned* dst = ws + ((size_t)s * NIMG + bc) * WORDS_PER_IMG;
    const uint4* sv = reinterpret_cast<const uint4*>(lh);
    uint4* dv = reinterpret_cast<uint4*>(dst);
    for (int i = tid; i < WORDS_PER_IMG / 4; i += 1024) dv[i] = sv[i];
}

// ---------- fallback: proven GROUPS=2 static-LDS kernel (R4) ----------
constexpr int GROUP_ROWS = 128;
constexpr int LDSW = GROUP_ROWS * (NBINS / 2);    // 64 KB
constexpr float QSCALE = 1024.0f;

struct QElem {
    int i0, q0, q1, ga0, ga1;
    unsigned r0, r1;
};

__device__ __forceinline__ QElem quantize2(float x, int lo) {
    QElem e;
    float fa = floorf(x);
    float w0 = 0.5f + 0.5f * cospi_fast(x - fa);
    e.i0 = (int)fa;
    e.q0 = (int)(w0 * QSCALE + 0.5f);
    e.q1 = QI - e.q0;
    int r0 = e.i0 - lo;
    e.ga0 = ((unsigned)r0 < (unsigned)GROUP_ROWS) ? e.q0 : 0;
    e.ga1 = ((unsigned)(r0 + 1) < (unsigned)GROUP_ROWS) ? e.q1 : 0;
    e.r0 = (unsigned)r0 & (GROUP_ROWS - 1);
    e.r1 = (unsigned)(r0 + 1) & (GROUP_ROWS - 1);
    return e;
}

__global__ __launch_bounds__(512, 4)
void hist2_kernel(const float* __restrict__ X, unsigned* __restrict__ ws) {
    __shared__ unsigned lh[LDSW];
    const int tid = threadIdx.x;
    const int g = blockIdx.x;
    const int bc = blockIdx.y;
    const int s = blockIdx.z;
    const int S = gridDim.z;
    const int lo = g * GROUP_ROWS;
    const float* col = X + (size_t)bc * IMG_ELEMS + tid;

    {
        uint4* lv = reinterpret_cast<uint4*>(lh);
        for (int i = tid; i < LDSW / 4; i += 512) lv[i] = make_uint4(0u, 0u, 0u, 0u);
    }
    __syncthreads();

    const int r_beg = (PAIR_ROWS * s) / S;
    const int r_end = (PAIR_ROWS * (s + 1)) / S;

    float cur[PF], nxt[PF];
#pragma unroll
    for (int j = 0; j < PF; ++j)
        cur[j] = col[(size_t)min(r_beg + 1 + j, PAIR_ROWS) * W_IMG];
    QElem a = quantize2(col[(size_t)r_beg * W_IMG], lo);

    for (int R = r_beg; R < r_end; R += PF) {
#pragma unroll
        for (int j = 0; j < PF; ++j)
            nxt[j] = col[(size_t)min(R + PF + 1 + j, PAIR_ROWS) * W_IMG];
#pragma unroll
        for (int j = 0; j < PF; ++j) {
            if (R + j < r_end) {
                QElem b = quantize2(cur[j], lo);
                if (a.ga0 | a.ga1) {
                    unsigned p00 = (unsigned)(a.ga0 * b.q0 + QI / 2) >> 10;
                    unsigned p01 = (unsigned)(a.ga0 * b.q1 + QI / 2) >> 10;
                    unsigned p10 = (unsigned)(a.ga1 * b.q0 + QI / 2) >> 10;
                    unsigned p11 = (unsigned)(a.ga1 * b.q1 + QI / 2) >> 10;
                    unsigned c0 = (unsigned)b.i0 >> 1;
                    unsigned c1 = (unsigned)(b.i0 + 1) >> 1;
                    unsigned sh0 = ((unsigned)b.i0 & 1u) << 4;
                    unsigned sh1 = sh0 ^ 16u;
                    atomicAdd(&lh[a.r0 * (NBINS / 2) + c0], p00 << sh0);
                    atomicAdd(&lh[a.r0 * (NBINS / 2) + c1], p01 << sh1);
                    atomicAdd(&lh[a.r1 * (NBINS / 2) + c0], p10 << sh0);
                    atomicAdd(&lh[a.r1 * (NBINS / 2) + c1], p11 << sh1);
                }
                a = b;
            }
        }
#pragma unroll
        for (int j = 0; j < PF; ++j) cur[j] = nxt[j];
    }
    __syncthreads();

    unsigned* dst = ws + ((size_t)s * NIMG + bc) * WORDS_PER_IMG + (size_t)g * LDSW;
    const uint4* sv = reinterpret_cast<const uint4*>(lh);
    uint4* dv = reinterpret_cast<uint4*>(dst);
    for (int i = tid; i < LDSW / 4; i += 512) dv[i] = sv[i];
}

// ---------- fused tail: sum slices + max + normalize, one block per image ----
// 32 register-held u32 sums/thread; u16 halves can't carry (max bin << 65535).
// Normalized ratio q/qmax makes the 1/1024 quant scale cancel exactly.
__global__ __launch_bounds__(1024, 4)
void finale_kernel(const unsigned* __restrict__ ws, float* __restrict__ out, int S) {
    const int bc = blockIdx.x;
    const int tid = threadIdx.x;
    const unsigned* base = ws + (size_t)bc * WORDS_PER_IMG;

    unsigned sum[32];
#pragma unroll
    for (int k = 0; k < 32; ++k) sum[k] = 0u;
    for (int s = 0; s < S; ++s) {
        const unsigned* p = base + (size_t)s * NIMG * WORDS_PER_IMG;
#pragma unroll
        for (int k = 0; k < 32; ++k) sum[k] += p[tid + k * 1024];
    }

    float m = 0.0f;
#pragma unroll
    for (int k = 0; k < 32; ++k) {
        m = fmaxf(m, (float)(sum[k] & 0xFFFFu));
        m = fmaxf(m, (float)(sum[k] >> 16));
    }
#pragma unroll
    for (int off = 32; off > 0; off >>= 1) m = fmaxf(m, __shfl_down(m, off, 64));
    __shared__ float sm[16];
    __shared__ float s_inv;
    if ((tid & 63) == 0) sm[tid >> 6] = m;
    __syncthreads();
    if (tid == 0) {
        float mm = sm[0];
#pragma unroll
        for (int i = 1; i < 16; ++i) mm = fmaxf(mm, sm[i]);
        s_inv = 1.0f / mm;
    }
    __syncthreads();
    const float inv = s_inv;

    float2* o = reinterpret_cast<float2*>(out + (size_t)bc * HIST);
#pragma unroll
    for (int k = 0; k < 32; ++k) {
        unsigned w = sum[k];
        o[tid + k * 1024] = make_float2((float)(w & 0xFFFFu) * inv,
                                        (float)(w >> 16) * inv);
    }
}

extern "C" void kernel_launch(void* const* d_in, const int* in_sizes, int n_in,
                              void* d_out, int out_size, void* d_ws, size_t ws_size,
                              hipStream_t stream) {
    const float* X = (const float*)d_in[0];
    float* out = (float*)d_out;
    unsigned* ws = (unsigned*)d_ws;

    const size_t slice_bytes = (size_t)NIMG * WORDS_PER_IMG * sizeof(unsigned); // 12 MB
    int S = 8;
    while (S > 1 && (size_t)S * slice_bytes > ws_size) S >>= 1;  // 8->4->2->1

    // Opt-in to 128 KB dynamic LDS (host-side attr set; graph-capture-safe,
    // idempotent). If unsupported, fall back to the proven 2-group kernel.
    hipError_t attr_ok = hipFuncSetAttribute(
        reinterpret_cast<const void*>(hist1_kernel),
        hipFuncAttributeMaxDynamicSharedMemorySize, WORDS_PER_IMG * 4);

    if (attr_ok == hipSuccess) {
        hist1_kernel<<<dim3(S, NIMG), 1024, WORDS_PER_IMG * 4, stream>>>(X, ws);
    } else {
        hist2_kernel<<<dim3(2, NIMG, S), 512, 0, stream>>>(X, ws);
    }

    finale_kernel<<<NIMG, 1024, 0, stream>>>(ws, out, S);
}